// Round 7
// baseline (263.127 us; speedup 1.0000x reference)
//
#include <hip/hip_runtime.h>
#include <hip/hip_fp16.h>

#define PENALTY_N 0.1f
#define NPART 4
#define CP 25024          // nodes per partition; 4*25024 = 100,096 >= 100,000
#define CBLK 256          // compute kernel block (4 waves)
#define NW 4              // waves per compute block
#define FL 512            // staging cap per (bucket,wave) = 64 lanes * 8 recs
#define SBLK 1024         // scatter block
#define MAX_BPP 64        // scatter slices/partition: 4*64 = 256 blocks = 1/CU

// ---------------------------------------------------------------------------
// init: zero bucket cursors and the scalar accumulator (must happen in a
// PRIOR kernel -- dispatch order within a kernel is undefined).
// ---------------------------------------------------------------------------
__global__ void init_kernel(unsigned* __restrict__ cursors,
                            float* __restrict__ out_scalar) {
    if (threadIdx.x < NPART) cursors[threadIdx.x] = 0u;
    if (threadIdx.x == NPART) *out_scalar = 0.0f;
}

// ---------------------------------------------------------------------------
// Phase A: gather traffic, compute t, emit 4B endpoint records bucketed by
// partition:  rec = local_idx(16) | half(+-t)<<16.
// LDS staging with PER-WAVE counters (<=16 lanes contend per counter; the 4
// counters of a wave sit in 4 distinct banks -> parallel). Flush every
// iteration: 1 global cursor atomic per bucket, then coalesced copies.
// ---------------------------------------------------------------------------
__global__ __launch_bounds__(CBLK, 4) void compute_bucket_kernel(
    const int* __restrict__ src_idx,
    const int* __restrict__ dst_idx,
    const float* __restrict__ w,
    const float* __restrict__ traffic,
    unsigned* __restrict__ gbuckets,   // [NPART][bcap]
    unsigned* __restrict__ cursors,    // [NPART]
    int nE, unsigned bcap) {
    __shared__ unsigned sbuf[NPART][NW][FL];   // 32 KB
    __shared__ unsigned scnt[NW][NPART];
    __shared__ unsigned sbase[NPART];

    const int tid = threadIdx.x;
    const int wid = tid >> 6;
    const int ngroups = (nE + 3) >> 2;
    const int gstep = gridDim.x * CBLK;

    const int4* __restrict__ s4p = (const int4*)src_idx;
    const int4* __restrict__ d4p = (const int4*)dst_idx;
    const float4* __restrict__ w4p = (const float4*)w;

    for (int base = blockIdx.x * CBLK; base < ngroups; base += gstep) {
        __syncthreads();   // previous copy phase still reads scnt
        if (tid < NW * NPART) ((unsigned*)scnt)[tid] = 0u;
        __syncthreads();

        const int v = base + tid;
        if (v < ngroups) {
            const int e0 = v << 2;
            int4 s, d;
            float4 ww;
            if (e0 + 3 < nE) {
                s = s4p[v];
                d = d4p[v];
                ww = w4p[v];
            } else {                    // guarded partial tail group
                int sa[4], da[4];
                float wa[4];
                for (int k = 0; k < 4; ++k) {
                    int e = e0 + k;
                    sa[k] = (e < nE) ? src_idx[e] : 0;
                    da[k] = (e < nE) ? dst_idx[e] : 0;
                    wa[k] = (e < nE) ? w[e] : 0.0f;
                }
                s = make_int4(sa[0], sa[1], sa[2], sa[3]);
                d = make_int4(da[0], da[1], da[2], da[3]);
                ww = make_float4(wa[0], wa[1], wa[2], wa[3]);
            }
            // 8 independent gathers issued before any use
            float a0 = traffic[s.x], a1 = traffic[s.y];
            float a2 = traffic[s.z], a3 = traffic[s.w];
            float b0 = traffic[d.x], b1 = traffic[d.y];
            float b2 = traffic[d.z], b3 = traffic[d.w];
            float t0 = fabsf(a0 - b0) * (PENALTY_N * ww.x);
            float t1 = fabsf(a1 - b1) * (PENALTY_N * ww.y);
            float t2 = fabsf(a2 - b2) * (PENALTY_N * ww.z);
            float t3 = fabsf(a3 - b3) * (PENALTY_N * ww.w);

#define STAGE(GI, VAL)                                                        \
            {                                                                 \
                unsigned gb_ = (unsigned)(GI) / (unsigned)CP;                 \
                unsigned lc_ = (unsigned)(GI) - gb_ * (unsigned)CP;           \
                unsigned hb_ =                                                \
                    (unsigned)__half_as_ushort(__float2half_rn(VAL));         \
                unsigned pos_ = atomicAdd(&scnt[wid][gb_], 1u);               \
                sbuf[gb_][wid][pos_] = lc_ | (hb_ << 16);                     \
            }
            /* e0 < nE guaranteed when v < ngroups */
            STAGE(s.x, -t0) STAGE(d.x, t0)
            if (e0 + 1 < nE) { STAGE(s.y, -t1) STAGE(d.y, t1) }
            if (e0 + 2 < nE) { STAGE(s.z, -t2) STAGE(d.z, t2) }
            if (e0 + 3 < nE) { STAGE(s.w, -t3) STAGE(d.w, t3) }
#undef STAGE
        }
        __syncthreads();
        if (tid < NPART) {
            unsigned tot = scnt[0][tid] + scnt[1][tid] +
                           scnt[2][tid] + scnt[3][tid];
            sbase[tid] = atomicAdd(&cursors[tid], tot);
        }
        __syncthreads();
        // coalesced bulk copy of the staged records
        for (int k = 0; k < NPART; ++k) {
            unsigned off = 0;
            unsigned* gk = gbuckets + (size_t)k * bcap;
            for (int wv = 0; wv < NW; ++wv) {
                unsigned c = scnt[wv][k];
                unsigned gb = sbase[k] + off;
                for (unsigned i = tid; i < c; i += CBLK) {
                    unsigned gi = gb + i;
                    if (gi < bcap) gk[gi] = sbuf[k][wv][i];
                }
                off += c;
            }
        }
    }
}

// ---------------------------------------------------------------------------
// Phase B: scatter. Block (p, slice) reads ONLY bucket p (each record read
// exactly once chip-wide) and does UNCONDITIONAL LDS atomics.
// ---------------------------------------------------------------------------
__global__ __launch_bounds__(SBLK, 4) void bucket_scatter_kernel(
    const unsigned* __restrict__ gbuckets,
    const unsigned* __restrict__ cursors,
    float* __restrict__ scratch,   // [NPART][Bpp][CP]
    int nN, int Bpp, unsigned bcap) {
    __shared__ float hist[CP];     // 100,096 B -> 1 block/CU

    const int p = blockIdx.x / Bpp;
    const int slice = blockIdx.x % Bpp;
    const int tid = threadIdx.x;
    const unsigned total = min(cursors[p], bcap);
    const unsigned csz = (unsigned)min(CP, nN - p * CP);

    {
        float4* h4 = (float4*)hist;
        for (int i = tid; i < CP / 4; i += SBLK)
            h4[i] = make_float4(0.f, 0.f, 0.f, 0.f);
    }
    __syncthreads();

    const unsigned* __restrict__ bp = gbuckets + (size_t)p * bcap;
    const uint4* __restrict__ b4 = (const uint4*)bp;
    const unsigned nv4 = total >> 2;
    const unsigned stride = (unsigned)(Bpp * SBLK);

#define PROC(R)                                                               \
    atomicAdd(&hist[(R) & 0xFFFFu],                                           \
              __half2float(__ushort_as_half((unsigned short)((R) >> 16))));

    for (unsigned i = (unsigned)(slice * SBLK + tid); i < nv4; i += stride) {
        uint4 q = b4[i];
        PROC(q.x) PROC(q.y) PROC(q.z) PROC(q.w)
    }
    for (unsigned e = (nv4 << 2) + (unsigned)(slice * SBLK + tid); e < total;
         e += stride) {
        unsigned r = bp[e];
        PROC(r)
    }
#undef PROC

    __syncthreads();
    float* dst = scratch + (size_t)blockIdx.x * CP;
    {
        const int n4 = (int)(csz >> 2);
        float4* d4 = (float4*)dst;
        const float4* h4 = (const float4*)hist;
        for (int i = tid; i < n4; i += SBLK) d4[i] = h4[i];
        for (int i = (n4 << 2) + tid; i < (int)csz; i += SBLK) dst[i] = hist[i];
    }
}

// ---------------------------------------------------------------------------
// Phase C: per-node sum of Bpp private copies + base traffic; writes
// new_traffic and fuses the service-efficiency reduction.
// ---------------------------------------------------------------------------
__global__ __launch_bounds__(256) void part_reduce_kernel(
    const float* __restrict__ scratch,
    const float* __restrict__ traffic,
    const float* __restrict__ yield_rate,
    const float* __restrict__ cost,
    float* __restrict__ out,        // [nN] new_traffic, out[nN] scalar
    int nN, int Bpp) {
    const int tid = blockIdx.x * blockDim.x + threadIdx.x;
    const int stride = gridDim.x * blockDim.x;

    float acc = 0.0f;
    for (int i = tid; i < nN; i += stride) {
        int p = i / CP;
        int off = i - p * CP;
        const float* base = scratch + (size_t)p * Bpp * CP + off;

        float s0 = traffic[i], s1 = 0.0f, s2 = 0.0f, s3 = 0.0f;
        int b = 0;
        for (; b + 8 <= Bpp; b += 8) {
            const float* q = base + (size_t)b * CP;
            float a0 = q[0 * (size_t)CP];
            float a1 = q[1 * (size_t)CP];
            float a2 = q[2 * (size_t)CP];
            float a3 = q[3 * (size_t)CP];
            float a4 = q[4 * (size_t)CP];
            float a5 = q[5 * (size_t)CP];
            float a6 = q[6 * (size_t)CP];
            float a7 = q[7 * (size_t)CP];
            s0 += a0 + a4;
            s1 += a1 + a5;
            s2 += a2 + a6;
            s3 += a3 + a7;
        }
        for (; b < Bpp; ++b) s0 += base[(size_t)b * CP];
        float s = (s0 + s1) + (s2 + s3);
        out[i] = s;
        acc = fmaf(yield_rate[i], s, acc) - cost[i];
    }

    #pragma unroll
    for (int off = 32; off > 0; off >>= 1) acc += __shfl_down(acc, off, 64);

    __shared__ float wsum[4];
    const int lane = threadIdx.x & 63;
    const int wid = threadIdx.x >> 6;
    if (lane == 0) wsum[wid] = acc;
    __syncthreads();
    if (threadIdx.x == 0)
        atomicAdd(&out[nN], wsum[0] + wsum[1] + wsum[2] + wsum[3]);
}

// ---------------------------------------------------------------------------
// Fallback path (ws too small / shape mismatch): direct-atomic version.
// ---------------------------------------------------------------------------
__global__ void init_out_kernel(const float* __restrict__ traffic,
                                float* __restrict__ out, int nN) {
    int i = blockIdx.x * blockDim.x + threadIdx.x;
    if (i < nN) out[i] = traffic[i];
    else if (i == nN) out[i] = 0.0f;
}

__global__ __launch_bounds__(256) void edge_scatter_kernel(
    const int* __restrict__ src_idx, const int* __restrict__ dst_idx,
    const float* __restrict__ w, const float* __restrict__ traffic,
    float* __restrict__ out, int nE) {
    const int tid = blockIdx.x * blockDim.x + threadIdx.x;
    const int stride = gridDim.x * blockDim.x;
    for (int e = tid; e < nE; e += stride) {
        int s = src_idx[e];
        int d = dst_idx[e];
        float t = fabsf(traffic[s] - traffic[d]) * (PENALTY_N * w[e]);
        atomicAdd(&out[s], -t);
        atomicAdd(&out[d], t);
    }
}

__global__ __launch_bounds__(256) void reduce_kernel(
    const float* __restrict__ new_traffic, const float* __restrict__ yield_rate,
    const float* __restrict__ cost, float* __restrict__ total, int nN) {
    const int tid = blockIdx.x * blockDim.x + threadIdx.x;
    const int stride = gridDim.x * blockDim.x;
    float acc = 0.0f;
    for (int i = tid; i < nN; i += stride)
        acc = fmaf(yield_rate[i], new_traffic[i], acc) - cost[i];
    #pragma unroll
    for (int off = 32; off > 0; off >>= 1) acc += __shfl_down(acc, off, 64);
    __shared__ float wsum[4];
    const int lane = threadIdx.x & 63;
    const int wid = threadIdx.x >> 6;
    if (lane == 0) wsum[wid] = acc;
    __syncthreads();
    if (threadIdx.x == 0)
        atomicAdd(total, wsum[0] + wsum[1] + wsum[2] + wsum[3]);
}

// ---------------------------------------------------------------------------
extern "C" void kernel_launch(void* const* d_in, const int* in_sizes, int n_in,
                              void* d_out, int out_size, void* d_ws, size_t ws_size,
                              hipStream_t stream) {
    const int* edge_index = (const int*)d_in[0];     // (2, E) flat
    const float* edge_weight = (const float*)d_in[1];
    const float* nodes_yield = (const float*)d_in[2];
    const float* nodes_traffic = (const float*)d_in[3];
    const float* nodes_cost = (const float*)d_in[4];
    float* out = (float*)d_out;

    const int nE = in_sizes[1];
    const int nN = in_sizes[2];
    const int* src_idx = edge_index;
    const int* dst_idx = edge_index + nE;

    // bucket capacity: expected 2*nE/NPART records, +10% slack (uniform
    // random節点 -> deviation is ~ +-0.1%; slack is >10 sigma), 1KB-rounded.
    size_t bcap = ((size_t)nE * 2u) / NPART;
    bcap += bcap / 10;
    bcap = (bcap + 1023) & ~(size_t)1023;
    size_t bucket_bytes = bcap * sizeof(unsigned) * NPART;

    size_t rem = (ws_size > bucket_bytes + 256)
                     ? (ws_size - bucket_bytes - 256) : 0;
    int Bpp = (int)(rem / ((size_t)NPART * CP * sizeof(float)));
    if (Bpp > MAX_BPP) Bpp = MAX_BPP;

    if (Bpp >= 16 && nN <= NPART * CP && bcap < 0x7FFFFFFFu) {
        unsigned* gbuckets = (unsigned*)d_ws;
        float* scratch = (float*)((char*)d_ws + bucket_bytes);
        unsigned* cursors = (unsigned*)((char*)d_ws + bucket_bytes +
                                        (size_t)NPART * Bpp * CP * sizeof(float));

        init_kernel<<<1, 64, 0, stream>>>(cursors, out + nN);
        compute_bucket_kernel<<<2048, CBLK, 0, stream>>>(
            src_idx, dst_idx, edge_weight, nodes_traffic,
            gbuckets, cursors, nE, (unsigned)bcap);
        bucket_scatter_kernel<<<NPART * Bpp, SBLK, 0, stream>>>(
            gbuckets, cursors, scratch, nN, Bpp, (unsigned)bcap);
        part_reduce_kernel<<<(nN + 255) / 256, 256, 0, stream>>>(
            scratch, nodes_traffic, nodes_yield, nodes_cost, out, nN, Bpp);
    } else {
        int grid = (nN + 1 + 255) / 256;
        init_out_kernel<<<grid, 256, 0, stream>>>(nodes_traffic, out, nN);
        edge_scatter_kernel<<<2048, 256, 0, stream>>>(src_idx, dst_idx,
                                                      edge_weight, nodes_traffic,
                                                      out, nE);
        reduce_kernel<<<256, 256, 0, stream>>>(out, nodes_yield, nodes_cost,
                                               out + nN, nN);
    }
}